// Round 9
// baseline (607.130 us; speedup 1.0000x reference)
//
#include <hip/hip_runtime.h>
#include <stdint.h>

#define BN_EPS 1e-5f
#define SCAN_G 128

typedef short short8 __attribute__((ext_vector_type(8)));
typedef float f32x4 __attribute__((ext_vector_type(4)));

__device__ __forceinline__ unsigned short f2bf(float f) {
    union { float f; unsigned int u; } v; v.f = f;
    unsigned int r = v.u + 0x7FFFu + ((v.u >> 16) & 1u);
    return (unsigned short)(r >> 16);
}
__device__ __forceinline__ float bf2f(unsigned short h) {
    union { unsigned int u; float f; } v; v.u = (unsigned int)h << 16; return v.f;
}

// ---------------- CSR build ----------------
__global__ void k_count(const int* __restrict__ dst, int* __restrict__ cnt, int E) {
    int i = blockIdx.x * 256 + threadIdx.x;
    if (i < E) atomicAdd(cnt + dst[i], 1);
}

__global__ __launch_bounds__(256) void k_scanA(const int* __restrict__ cnt,
                                               int* __restrict__ bsum, int N) {
    __shared__ int red[256];
    int b = blockIdx.x, t = threadIdx.x;
    int C = (N + SCAN_G - 1) / SCAN_G;
    int c = (C + 255) >> 8;
    int lo = b * C + t * c;
    int hi = min(lo + c, min((b + 1) * C, N));
    int s = 0;
    for (int i = lo; i < hi; ++i) s += cnt[i];
    red[t] = s;
    __syncthreads();
    for (int off = 128; off > 0; off >>= 1) {
        if (t < off) red[t] += red[t + off];
        __syncthreads();
    }
    if (t == 0) bsum[b] = red[0];
}
__global__ void k_scanB(const int* __restrict__ bsum, int* __restrict__ boff,
                        int* __restrict__ rowptr, int N) {
    __shared__ int sh[SCAN_G];
    int t = threadIdx.x;
    int v = bsum[t];
    sh[t] = v;
    __syncthreads();
    for (int off = 1; off < SCAN_G; off <<= 1) {
        int add = (t >= off) ? sh[t - off] : 0;
        __syncthreads();
        sh[t] += add;
        __syncthreads();
    }
    boff[t] = sh[t] - v;
    if (t == SCAN_G - 1) rowptr[N] = sh[t];
}
__global__ __launch_bounds__(256) void k_scanC(const int* __restrict__ cnt,
                                               const int* __restrict__ boff,
                                               int* __restrict__ rowptr, int N) {
    __shared__ int sh[256];
    int b = blockIdx.x, t = threadIdx.x;
    int C = (N + SCAN_G - 1) / SCAN_G;
    int c = (C + 255) >> 8;
    int lo = b * C + t * c;
    int hi = min(lo + c, min((b + 1) * C, N));
    int s = 0;
    for (int i = lo; i < hi; ++i) s += cnt[i];
    sh[t] = s;
    __syncthreads();
    for (int off = 1; off < 256; off <<= 1) {
        int add = (t >= off) ? sh[t - off] : 0;
        __syncthreads();
        sh[t] += add;
        __syncthreads();
    }
    int run = boff[b] + sh[t] - s;
    for (int i = lo; i < hi; ++i) { rowptr[i] = run; run += cnt[i]; }
}

__global__ void k_fill(const int* __restrict__ src, const int* __restrict__ dst,
                       const int* __restrict__ rowptr, int* __restrict__ cursor,
                       int* __restrict__ srcs, int E) {
    int i = blockIdx.x * 256 + threadIdx.x;
    if (i < E) {
        int r = dst[i];
        int p = atomicAdd(cursor + r, 1);
        srcs[rowptr[r] + p] = src[i];
    }
}

// ---------------- weight convert+transpose to bf16 [Nn][K] (+ cls_w) ----------------
__global__ void k_convw(const float* __restrict__ Wg, const float* __restrict__ W1,
                        const float* __restrict__ W2, const float* __restrict__ Wc,
                        unsigned short* __restrict__ WgT, unsigned short* __restrict__ W1T,
                        unsigned short* __restrict__ W2T, unsigned short* __restrict__ WcT) {
    int id = blockIdx.x * 256 + threadIdx.x;
    if (id < 2 * 16384) {
        int L = id >> 14, e = id & 16383;
        int k = e >> 7, n = e & 127;
        WgT[(L << 14) + n * 128 + k] = f2bf(Wg[id]);
    } else if (id < 2 * 16384 + 2 * 65536) {
        int t = id - 2 * 16384;
        int L = t >> 16, e = t & 65535;
        int k = e >> 9, n = e & 511;
        W1T[(L << 16) + n * 128 + k] = f2bf(W1[t]);
    } else if (id < 2 * 16384 + 4 * 65536) {
        int t = id - 2 * 16384 - 2 * 65536;
        int L = t >> 16, e = t & 65535;
        int k = e >> 7, n = e & 127;
        W2T[(L << 16) + n * 512 + k] = f2bf(W2[t]);
    } else if (id < 2 * 16384 + 4 * 65536 + 2048) {
        int t = id - 2 * 16384 - 4 * 65536;
        int k = t >> 4, c = t & 15;
        WcT[c * 128 + k] = f2bf(Wc[t]);
    }
}

// nodes f32 -> bf16 (packed)
__global__ void k_convn(const float* __restrict__ nf, unsigned short* __restrict__ nbf, int n2) {
    for (int i = blockIdx.x * 256 + threadIdx.x; i < n2; i += gridDim.x * 256) {
        float2 v = ((const float2*)nf)[i];
        ((unsigned int*)nbf)[i] = ((unsigned int)f2bf(v.y) << 16) | (unsigned int)f2bf(v.x);
    }
}

// ---------------- aggregation: one HALF-WAVE (32 lanes) per dst node ----------------
__global__ __launch_bounds__(256) void k_agg(
    const unsigned short* __restrict__ xbf, const int* __restrict__ rowptr,
    const int* __restrict__ srcs, unsigned short* __restrict__ aggbf, int N) {
    int gh = (blockIdx.x * 256 + threadIdx.x) >> 5;
    int l = threadIdx.x & 31;
    if (gh >= N) return;
    int lo = rowptr[gh], hi = rowptr[gh + 1];
    float a0 = 0.f, a1 = 0.f, a2 = 0.f, a3 = 0.f;
    const uint2* x2 = (const uint2*)xbf;
    int j = lo;
    for (; j + 4 <= hi; j += 4) {
        int s0 = srcs[j], s1 = srcs[j + 1], s2 = srcs[j + 2], s3 = srcs[j + 3];
        uint2 p0 = x2[(size_t)s0 * 32 + l];
        uint2 p1 = x2[(size_t)s1 * 32 + l];
        uint2 p2 = x2[(size_t)s2 * 32 + l];
        uint2 p3 = x2[(size_t)s3 * 32 + l];
        a0 += bf2f((unsigned short)p0.x) + bf2f((unsigned short)p1.x)
            + bf2f((unsigned short)p2.x) + bf2f((unsigned short)p3.x);
        a1 += bf2f((unsigned short)(p0.x >> 16)) + bf2f((unsigned short)(p1.x >> 16))
            + bf2f((unsigned short)(p2.x >> 16)) + bf2f((unsigned short)(p3.x >> 16));
        a2 += bf2f((unsigned short)p0.y) + bf2f((unsigned short)p1.y)
            + bf2f((unsigned short)p2.y) + bf2f((unsigned short)p3.y);
        a3 += bf2f((unsigned short)(p0.y >> 16)) + bf2f((unsigned short)(p1.y >> 16))
            + bf2f((unsigned short)(p2.y >> 16)) + bf2f((unsigned short)(p3.y >> 16));
    }
    for (; j < hi; ++j) {
        uint2 p = x2[(size_t)srcs[j] * 32 + l];
        a0 += bf2f((unsigned short)p.x); a1 += bf2f((unsigned short)(p.x >> 16));
        a2 += bf2f((unsigned short)p.y); a3 += bf2f((unsigned short)(p.y >> 16));
    }
    float iw = 1.0f / fmaxf((float)(hi - lo), 1.0f);
    uint2 o;
    o.x = ((unsigned)f2bf(a1 * iw) << 16) | (unsigned)f2bf(a0 * iw);
    o.y = ((unsigned)f2bf(a3 * iw) << 16) | (unsigned)f2bf(a2 * iw);
    ((uint2*)aggbf)[(size_t)gh * 32 + l] = o;
}

// ---------------- bf16 MFMA GEMM (GCN mixer): C = A @ BT^T + bias + res, +BN stats ----
template<bool RELU, bool HASB, bool RES, bool OUTBF, bool STATS>
__global__ __launch_bounds__(256) void k_mgemm(
    const unsigned short* __restrict__ A, const unsigned short* __restrict__ BT,
    const float* __restrict__ bias, const unsigned short* __restrict__ res,
    float* __restrict__ Cf, unsigned short* __restrict__ Cbf,
    float* __restrict__ sums, int M, int Nn, int K) {
    __shared__ short As[128 * 32];
    __shared__ short Bs[128 * 32];
    int tid = threadIdx.x;
    int lane = tid & 63;
    int wid = tid >> 6;
    int wr = wid >> 1, wc = wid & 1;
    int row0 = blockIdx.x * 128, col0 = blockIdx.y * 128;
    int lm = lane & 15, hk = lane >> 4;

    int sr = tid >> 2, ss = tid & 3;
    int wsw = sr * 32 + ((ss ^ ((sr >> 1) & 3)) << 3);
    const unsigned short* gA = A + (size_t)(row0 + sr) * K + ss * 8;
    const unsigned short* gB = BT + (size_t)(col0 + sr) * K + ss * 8;

    int oA[4], oB[4];
#pragma unroll
    for (int i = 0; i < 4; ++i) {
        int ra = wr * 64 + i * 16 + lm;
        oA[i] = ra * 32 + ((hk ^ ((ra >> 1) & 3)) << 3);
        int rb = wc * 64 + i * 16 + lm;
        oB[i] = rb * 32 + ((hk ^ ((rb >> 1) & 3)) << 3);
    }

    f32x4 acc[4][4] = {};
    for (int k0 = 0; k0 < K; k0 += 32) {
        short8 va0 = *(const short8*)(gA + k0);
        short8 va1 = *(const short8*)(gA + (size_t)64 * K + k0);
        short8 vb0 = *(const short8*)(gB + k0);
        short8 vb1 = *(const short8*)(gB + (size_t)64 * K + k0);
        __syncthreads();
        *(short8*)&As[wsw] = va0;
        *(short8*)&As[wsw + 64 * 32] = va1;
        *(short8*)&Bs[wsw] = vb0;
        *(short8*)&Bs[wsw + 64 * 32] = vb1;
        __syncthreads();
        short8 a[4], b[4];
#pragma unroll
        for (int i = 0; i < 4; ++i) a[i] = *(const short8*)&As[oA[i]];
#pragma unroll
        for (int j = 0; j < 4; ++j) b[j] = *(const short8*)&Bs[oB[j]];
#pragma unroll
        for (int i = 0; i < 4; ++i)
#pragma unroll
            for (int j = 0; j < 4; ++j)
                acc[i][j] = __builtin_amdgcn_mfma_f32_16x16x32_bf16(a[i], b[j], acc[i][j], 0, 0, 0);
    }

    float th_s[4] = {0.f, 0.f, 0.f, 0.f}, th_q[4] = {0.f, 0.f, 0.f, 0.f};
#pragma unroll
    for (int j = 0; j < 4; ++j) {
        int col = col0 + wc * 64 + j * 16 + lm;
        float bj = 0.f;
        if (HASB) bj = bias[col];
#pragma unroll
        for (int i = 0; i < 4; ++i) {
#pragma unroll
            for (int r = 0; r < 4; ++r) {
                int row = row0 + wr * 64 + i * 16 + hk * 4 + r;
                if (row < M) {
                    float v = acc[i][j][r] + bj;
                    if (RES) v += bf2f(res[(size_t)row * Nn + col]);
                    if (RELU) v = fmaxf(v, 0.f);
                    if (STATS) { th_s[j] += v; th_q[j] += v * v; }
                    if (OUTBF) Cbf[(size_t)row * Nn + col] = f2bf(v);
                    else Cf[(size_t)row * Nn + col] = v;
                }
            }
        }
    }
    if (STATS) {
#pragma unroll
        for (int j = 0; j < 4; ++j) {
            float s = th_s[j], q = th_q[j];
            s += __shfl_xor(s, 16); s += __shfl_xor(s, 32);
            q += __shfl_xor(q, 16); q += __shfl_xor(q, 32);
            if (hk == 0) {
                int col = col0 + wc * 64 + j * 16 + lm;
                atomicAdd(&sums[col], s);
                atomicAdd(&sums[128 + col], q);
            }
        }
    }
}

// ---------------- fused FF block v3: bn1 + FF1 + FF2 + res + BN2 stats ----------------
// 64 rows/block, 4 waves x 16 rows. X in swizzled LDS subtiles (k_mgemm pattern, 0-conflict);
// W1/W2 fragments read directly from global (L2-resident); NO in-loop barriers;
// y^T in registers, repack via 8 ds_bpermute per chunk.
#define SUBT 2064   // subtile stride in elems: 64*32 + 16 (rotates banks per subtile)
__global__ __launch_bounds__(256, 4) void k_ffused(
    float* __restrict__ t, const float* __restrict__ sums,
    const float* __restrict__ g, const float* __restrict__ b,
    const unsigned short* __restrict__ W1T, const float* __restrict__ b1,
    const unsigned short* __restrict__ W2T,
    float* __restrict__ sums2, int M, float invN) {
    __shared__ short Xs[4 * SUBT];    // 16.5KB  bn1(t) bf16, swizzled
    __shared__ float sa[128], sc[128];
    __shared__ float b1s[512];
    __shared__ float ssum[256];

    int tid = threadIdx.x;
    int row0 = blockIdx.x * 64;
    if (tid < 128) {
        float m = sums[tid] * invN;
        float var = sums[128 + tid] * invN - m * m;
        float a = g[tid] * rsqrtf(var + BN_EPS);
        sa[tid] = a; sc[tid] = b[tid] - m * a;
    }
    b1s[tid] = b1[tid];
    b1s[tid + 256] = b1[tid + 256];
    ssum[tid] = 0.f;
    __syncthreads();

    // prologue: 64 rows of t -> bn1 -> bf16 Xs (swizzled 16B slots)
    {
        int pc = (tid & 31) * 4;          // global col 0..124
        int pr = tid >> 5;                // row base 0..7
        int k0 = pc >> 5, cc = pc & 31;
        int slot = cc >> 3, off = cc & 7; // off in {0,4}
        float a0 = sa[pc], a1 = sa[pc + 1], a2 = sa[pc + 2], a3 = sa[pc + 3];
        float c0 = sc[pc], c1 = sc[pc + 1], c2 = sc[pc + 2], c3 = sc[pc + 3];
#pragma unroll
        for (int i = 0; i < 8; ++i) {
            int row = pr + i * 8;
            float4 v = *(const float4*)(t + (size_t)(row0 + row) * 128 + pc);
            unsigned int lo = ((unsigned)f2bf(v.y * a1 + c1) << 16) | (unsigned)f2bf(v.x * a0 + c0);
            unsigned int hi = ((unsigned)f2bf(v.w * a3 + c3) << 16) | (unsigned)f2bf(v.z * a2 + c2);
            int sw = slot ^ ((row >> 1) & 3);
            *(uint2*)&Xs[k0 * SUBT + row * 32 + sw * 8 + off] = make_uint2(lo, hi);
        }
    }
    __syncthreads();

    int lane = tid & 63, wv = tid >> 6;
    int lm = lane & 15, hk = lane >> 4;
    int mh = hk & 2;
    int idxA = 4 * (lm + 16 * ((2 * hk) & 3));
    int idxB = idxA + 64;
    int xrow = wv * 16 + lm;
    int xoff[4];
#pragma unroll
    for (int k0 = 0; k0 < 4; ++k0)
        xoff[k0] = k0 * SUBT + xrow * 32 + ((hk ^ ((xrow >> 1) & 3)) << 3);

    f32x4 tacc[8] = {};
#pragma unroll 2
    for (int hc = 0; hc < 16; ++hc) {
        // FF1 transposed: yT = W1c(h x k) @ X^T; A-fragments straight from global (L2)
        const unsigned short* w1p = W1T + (size_t)(hc * 32 + lm) * 128 + hk * 8;
        f32x4 y0 = {}, y1 = {};
#pragma unroll
        for (int k0 = 0; k0 < 4; ++k0) {
            short8 xf  = *(const short8*)&Xs[xoff[k0]];
            short8 w1a = *(const short8*)(w1p + k0 * 32);
            short8 w1b = *(const short8*)(w1p + 16 * 128 + k0 * 32);
            y0 = __builtin_amdgcn_mfma_f32_16x16x32_bf16(w1a, xf, y0, 0, 0, 0);
            y1 = __builtin_amdgcn_mfma_f32_16x16x32_bf16(w1b, xf, y1, 0, 0, 0);
        }
        // bias + relu + pack (h = hc*32 + m*16 + hk*4 + r)
        int bb = hc * 32 + hk * 4;
        float v00 = fmaxf(y0[0] + b1s[bb + 0], 0.f);
        float v01 = fmaxf(y0[1] + b1s[bb + 1], 0.f);
        float v02 = fmaxf(y0[2] + b1s[bb + 2], 0.f);
        float v03 = fmaxf(y0[3] + b1s[bb + 3], 0.f);
        float v10 = fmaxf(y1[0] + b1s[bb + 16], 0.f);
        float v11 = fmaxf(y1[1] + b1s[bb + 17], 0.f);
        float v12 = fmaxf(y1[2] + b1s[bb + 18], 0.f);
        float v13 = fmaxf(y1[3] + b1s[bb + 19], 0.f);
        int pk00 = (int)(((unsigned)f2bf(v01) << 16) | (unsigned)f2bf(v00));
        int pk01 = (int)(((unsigned)f2bf(v03) << 16) | (unsigned)f2bf(v02));
        int pk10 = (int)(((unsigned)f2bf(v11) << 16) | (unsigned)f2bf(v10));
        int pk11 = (int)(((unsigned)f2bf(v13) << 16) | (unsigned)f2bf(v12));
        // repack: lane(lm,hk) gathers h = 8hk..8hk+7 for node-row lm
        int q0a = __builtin_amdgcn_ds_bpermute(idxA, pk00);
        int q1a = __builtin_amdgcn_ds_bpermute(idxA, pk01);
        int q2a = __builtin_amdgcn_ds_bpermute(idxA, pk10);
        int q3a = __builtin_amdgcn_ds_bpermute(idxA, pk11);
        int q0b = __builtin_amdgcn_ds_bpermute(idxB, pk00);
        int q1b = __builtin_amdgcn_ds_bpermute(idxB, pk01);
        int q2b = __builtin_amdgcn_ds_bpermute(idxB, pk10);
        int q3b = __builtin_amdgcn_ds_bpermute(idxB, pk11);
        union { int u[4]; short8 s; } yf;
        yf.u[0] = mh ? q2a : q0a;
        yf.u[1] = mh ? q3a : q1a;
        yf.u[2] = mh ? q2b : q0b;
        yf.u[3] = mh ? q3b : q1b;
        // FF2: tacc += y @ W2c; B-fragments straight from global (L2)
        const unsigned short* w2p = W2T + (size_t)lm * 512 + hc * 32 + hk * 8;
#pragma unroll
        for (int nc = 0; nc < 8; ++nc) {
            short8 w2f = *(const short8*)(w2p + (size_t)nc * 16 * 512);
            tacc[nc] = __builtin_amdgcn_mfma_f32_16x16x32_bf16(yf.s, w2f, tacc[nc], 0, 0, 0);
        }
    }

    // epilogue: t = tacc + res(Xs), BN2 stats
#pragma unroll
    for (int nc = 0; nc < 8; ++nc) {
        int n = nc * 16 + lm;
        int k0 = n >> 5, cc = n & 31;
        int slot = cc >> 3, off = cc & 7;
        float s = 0.f, q = 0.f;
#pragma unroll
        for (int r = 0; r < 4; ++r) {
            int rloc = wv * 16 + hk * 4 + r;
            int grow = row0 + rloc;
            float res = bf2f((unsigned short)Xs[k0 * SUBT + rloc * 32 +
                                               ((slot ^ ((rloc >> 1) & 3)) << 3) + off]);
            float v = tacc[nc][r] + res;
            if (grow < M) {
                t[(size_t)grow * 128 + n] = v;
                s += v; q += v * v;
            }
        }
        s += __shfl_xor(s, 16); s += __shfl_xor(s, 32);
        q += __shfl_xor(q, 16); q += __shfl_xor(q, 32);
        if (hk == 0) {
            atomicAdd(&ssum[n], s);
            atomicAdd(&ssum[128 + n], q);
        }
    }
    __syncthreads();
    atomicAdd(&sums2[tid], ssum[tid]);
}

// ---------------- BN apply: x_bf = bf16((t - m) * a + b) ----------------
__global__ __launch_bounds__(256) void k_bnapply(
    const float* __restrict__ t, const float* __restrict__ sums,
    const float* __restrict__ g, const float* __restrict__ b,
    unsigned short* __restrict__ xbf, int N, float invN) {
    __shared__ float sa[128], sc[128];
    int tid = threadIdx.x;
    if (tid < 128) {
        float m = sums[tid] * invN;
        float var = sums[128 + tid] * invN - m * m;
        float a = g[tid] * rsqrtf(var + BN_EPS);
        sa[tid] = a; sc[tid] = b[tid] - m * a;
    }
    __syncthreads();
    int total4 = N * 32;
    for (int i = blockIdx.x * 256 + tid; i < total4; i += gridDim.x * 256) {
        int c4 = (i & 31) * 4;
        float4 v = ((const float4*)t)[i];
        float ox = v.x * sa[c4 + 0] + sc[c4 + 0];
        float oy = v.y * sa[c4 + 1] + sc[c4 + 1];
        float oz = v.z * sa[c4 + 2] + sc[c4 + 2];
        float ow = v.w * sa[c4 + 3] + sc[c4 + 3];
        uint2 pk;
        pk.x = ((unsigned)f2bf(oy) << 16) | (unsigned)f2bf(ox);
        pk.y = ((unsigned)f2bf(ow) << 16) | (unsigned)f2bf(oz);
        ((uint2*)xbf)[i] = pk;
    }
}

// ---------------- classifier: MFMA, one wave per 16-row tile ----------------
__global__ __launch_bounds__(256) void k_cls(
    const unsigned short* __restrict__ xbf, const unsigned short* __restrict__ wT,
    const float* __restrict__ bias, float* __restrict__ out, int N) {
    int wv = (blockIdx.x * 256 + threadIdx.x) >> 6;
    int lane = threadIdx.x & 63;
    int lm = lane & 15, hk = lane >> 4;
    int r0 = wv * 16;
    f32x4 acc = {};
    const unsigned short* xr = xbf + (size_t)(r0 + lm) * 128 + hk * 8;
    const unsigned short* wr = wT + lm * 128 + hk * 8;
#pragma unroll
    for (int ks = 0; ks < 4; ++ks) {
        short8 a = *(const short8*)(xr + ks * 32);
        short8 b = *(const short8*)(wr + ks * 32);
        acc = __builtin_amdgcn_mfma_f32_16x16x32_bf16(a, b, acc, 0, 0, 0);
    }
    float bv = bias[lm];
#pragma unroll
    for (int r = 0; r < 4; ++r) {
        int row = r0 + hk * 4 + r;
        if (row < N) out[(size_t)row * 16 + lm] = acc[r] + bv;
    }
}

extern "C" void kernel_launch(void* const* d_in, const int* in_sizes, int n_in,
                              void* d_out, int out_size, void* d_ws, size_t ws_size,
                              hipStream_t stream) {
    const float* nodes = (const float*)d_in[0];
    const float* W_gcn = (const float*)d_in[1];
    const float* b_gcn = (const float*)d_in[2];
    const float* bn1_g = (const float*)d_in[3];
    const float* bn1_b = (const float*)d_in[4];
    const float* bn2_g = (const float*)d_in[5];
    const float* bn2_b = (const float*)d_in[6];
    const float* ff_w1 = (const float*)d_in[7];
    const float* ff_b1 = (const float*)d_in[8];
    const float* ff_w2 = (const float*)d_in[9];
    const float* cls_w = (const float*)d_in[10];
    const float* cls_b = (const float*)d_in[11];
    const int* esrc = (const int*)d_in[12];
    const int* edst = (const int*)d_in[13];
    const int N = in_sizes[0] / 128;
    const int E = in_sizes[12];
    const int M_pad = (N + 127) & ~127;

    char* p = (char*)d_ws;
    auto alloc = [&](size_t bytes) {
        void* r = (void*)p;
        p += (bytes + 255) & ~(size_t)255;
        return r;
    };
    // zero-region: cnt | cursor | 4x sums  (one memset)
    int* cnt      = (int*)alloc((size_t)N * 4);
    int* cursor   = (int*)alloc((size_t)N * 4);
    float* sums4  = (float*)alloc(4 * 256 * 4);
    size_t zbytes = (size_t)((char*)sums4 + 4 * 256 * 4 - (char*)cnt);

    float* t    = (float*)alloc((size_t)M_pad * 128 * 4);
    int* rowptr = (int*)alloc((size_t)(N + 1) * 4);
    int* srcs   = (int*)alloc((size_t)E * 4);
    int* bsum   = (int*)alloc(SCAN_G * 4);
    int* boff   = (int*)alloc(SCAN_G * 4);
    unsigned short* nodes_bf = (unsigned short*)alloc((size_t)M_pad * 128 * 2);
    unsigned short* agg_bf   = (unsigned short*)alloc((size_t)M_pad * 128 * 2);
    unsigned short* x_bf     = (unsigned short*)alloc((size_t)M_pad * 128 * 2);
    unsigned short* WgT = (unsigned short*)alloc(2 * 128 * 128 * 2);
    unsigned short* W1T = (unsigned short*)alloc(2 * 512 * 128 * 2);
    unsigned short* W2T = (unsigned short*)alloc(2 * 128 * 512 * 2);
    unsigned short* WcT = (unsigned short*)alloc(16 * 128 * 2);

    hipMemsetAsync(cnt, 0, zbytes, stream);
    k_count<<<(E + 255) / 256, 256, 0, stream>>>(edst, cnt, E);
    k_scanA<<<SCAN_G, 256, 0, stream>>>(cnt, bsum, N);
    k_scanB<<<1, SCAN_G, 0, stream>>>(bsum, boff, rowptr, N);
    k_scanC<<<SCAN_G, 256, 0, stream>>>(cnt, boff, rowptr, N);
    k_fill<<<(E + 255) / 256, 256, 0, stream>>>(esrc, edst, rowptr, cursor, srcs, E);
    k_convw<<<1160, 256, 0, stream>>>(W_gcn, ff_w1, ff_w2, cls_w, WgT, W1T, W2T, WcT);
    k_convn<<<1600, 256, 0, stream>>>(nodes, nodes_bf, N * 64);

    const float invN = 1.0f / (float)N;
    const int MB = M_pad / 128;
    const int MB64 = M_pad / 64;
    const unsigned short* cur_bf = nodes_bf;
    for (int L = 0; L < 2; ++L) {
        k_agg<<<(N + 7) / 8, 256, 0, stream>>>(cur_bf, rowptr, srcs, agg_bf, N);
        float* s1 = sums4 + (L * 2 + 0) * 256;
        float* s2 = sums4 + (L * 2 + 1) * 256;
        // GCN: t = agg@Wg + b + res(cur_bf), f32 out, fused BN1 stats
        k_mgemm<false, true, true, false, true><<<dim3(MB, 1), 256, 0, stream>>>(
            agg_bf, WgT + (size_t)L * 16384, b_gcn + L * 128, cur_bf, t, nullptr, s1,
            N, 128, 128);
        // fused: bn1-apply + FF1 + FF2 + residual + BN2 stats (y in registers)
        k_ffused<<<MB64, 256, 0, stream>>>(
            t, s1, bn1_g + L * 128, bn1_b + L * 128,
            W1T + (size_t)L * 65536, ff_b1 + L * 512, W2T + (size_t)L * 65536,
            s2, N, invN);
        k_bnapply<<<1600, 256, 0, stream>>>(t, s2, bn2_g + L * 128, bn2_b + L * 128,
                                            x_bf, N, invN);
        cur_bf = x_bf;
    }
    k_cls<<<(M_pad / 16 + 3) / 4, 256, 0, stream>>>(x_bf, WcT, cls_b, (float*)d_out, N);
}

// Round 10
// 460.174 us; speedup vs baseline: 1.3193x; 1.3193x over previous
//
#include <hip/hip_runtime.h>
#include <stdint.h>

#define BN_EPS 1e-5f
#define SCAN_G 128

typedef short short8 __attribute__((ext_vector_type(8)));
typedef float f32x4 __attribute__((ext_vector_type(4)));

__device__ __forceinline__ unsigned short f2bf(float f) {
    union { float f; unsigned int u; } v; v.f = f;
    unsigned int r = v.u + 0x7FFFu + ((v.u >> 16) & 1u);
    return (unsigned short)(r >> 16);
}
__device__ __forceinline__ float bf2f(unsigned short h) {
    union { unsigned int u; float f; } v; v.u = (unsigned int)h << 16; return v.f;
}

// ---------------- CSR build ----------------
__global__ void k_count(const int* __restrict__ dst, int* __restrict__ cnt, int E) {
    int i = blockIdx.x * 256 + threadIdx.x;
    if (i < E) atomicAdd(cnt + dst[i], 1);
}

__global__ __launch_bounds__(256) void k_scanA(const int* __restrict__ cnt,
                                               int* __restrict__ bsum, int N) {
    __shared__ int red[256];
    int b = blockIdx.x, t = threadIdx.x;
    int C = (N + SCAN_G - 1) / SCAN_G;
    int c = (C + 255) >> 8;
    int lo = b * C + t * c;
    int hi = min(lo + c, min((b + 1) * C, N));
    int s = 0;
    for (int i = lo; i < hi; ++i) s += cnt[i];
    red[t] = s;
    __syncthreads();
    for (int off = 128; off > 0; off >>= 1) {
        if (t < off) red[t] += red[t + off];
        __syncthreads();
    }
    if (t == 0) bsum[b] = red[0];
}
__global__ void k_scanB(const int* __restrict__ bsum, int* __restrict__ boff,
                        int* __restrict__ rowptr, int N) {
    __shared__ int sh[SCAN_G];
    int t = threadIdx.x;
    int v = bsum[t];
    sh[t] = v;
    __syncthreads();
    for (int off = 1; off < SCAN_G; off <<= 1) {
        int add = (t >= off) ? sh[t - off] : 0;
        __syncthreads();
        sh[t] += add;
        __syncthreads();
    }
    boff[t] = sh[t] - v;
    if (t == SCAN_G - 1) rowptr[N] = sh[t];
}
__global__ __launch_bounds__(256) void k_scanC(const int* __restrict__ cnt,
                                               const int* __restrict__ boff,
                                               int* __restrict__ rowptr, int N) {
    __shared__ int sh[256];
    int b = blockIdx.x, t = threadIdx.x;
    int C = (N + SCAN_G - 1) / SCAN_G;
    int c = (C + 255) >> 8;
    int lo = b * C + t * c;
    int hi = min(lo + c, min((b + 1) * C, N));
    int s = 0;
    for (int i = lo; i < hi; ++i) s += cnt[i];
    sh[t] = s;
    __syncthreads();
    for (int off = 1; off < 256; off <<= 1) {
        int add = (t >= off) ? sh[t - off] : 0;
        __syncthreads();
        sh[t] += add;
        __syncthreads();
    }
    int run = boff[b] + sh[t] - s;
    for (int i = lo; i < hi; ++i) { rowptr[i] = run; run += cnt[i]; }
}

__global__ void k_fill(const int* __restrict__ src, const int* __restrict__ dst,
                       const int* __restrict__ rowptr, int* __restrict__ cursor,
                       int* __restrict__ srcs, int E) {
    int i = blockIdx.x * 256 + threadIdx.x;
    if (i < E) {
        int r = dst[i];
        int p = atomicAdd(cursor + r, 1);
        srcs[rowptr[r] + p] = src[i];
    }
}

// ------- combined convert: weights (transposed bf16) + cls_w + nodes bf16 -------
__global__ void k_conv(const float* __restrict__ Wg, const float* __restrict__ W1,
                       const float* __restrict__ W2, const float* __restrict__ Wc,
                       const float* __restrict__ nf,
                       unsigned short* __restrict__ WgT, unsigned short* __restrict__ W1T,
                       unsigned short* __restrict__ W2T, unsigned short* __restrict__ WcT,
                       unsigned short* __restrict__ nbf, int n2) {
    int id = blockIdx.x * 256 + threadIdx.x;
    const int A = 2 * 16384, B = A + 2 * 65536, C = B + 2 * 65536, D = C + 2048;
    if (id < A) {
        int L = id >> 14, e = id & 16383;
        int k = e >> 7, n = e & 127;
        WgT[(L << 14) + n * 128 + k] = f2bf(Wg[id]);
    } else if (id < B) {
        int t = id - A;
        int L = t >> 16, e = t & 65535;
        int k = e >> 9, n = e & 511;
        W1T[(L << 16) + n * 128 + k] = f2bf(W1[t]);
    } else if (id < C) {
        int t = id - B;
        int L = t >> 16, e = t & 65535;
        int k = e >> 7, n = e & 127;
        W2T[(L << 16) + n * 512 + k] = f2bf(W2[t]);
    } else if (id < D) {
        int t = id - C;
        int k = t >> 4, c = t & 15;
        WcT[c * 128 + k] = f2bf(Wc[t]);
    } else {
        int i = id - D;
        if (i < n2) {
            float2 v = ((const float2*)nf)[i];
            ((unsigned int*)nbf)[i] = ((unsigned int)f2bf(v.y) << 16) | (unsigned int)f2bf(v.x);
        }
    }
}

// ---------------- aggregation: one HALF-WAVE (32 lanes) per dst node ----------------
__global__ __launch_bounds__(256) void k_agg(
    const unsigned short* __restrict__ xbf, const int* __restrict__ rowptr,
    const int* __restrict__ srcs, unsigned short* __restrict__ aggbf, int N) {
    int gh = (blockIdx.x * 256 + threadIdx.x) >> 5;
    int l = threadIdx.x & 31;
    if (gh >= N) return;
    int lo = rowptr[gh], hi = rowptr[gh + 1];
    float a0 = 0.f, a1 = 0.f, a2 = 0.f, a3 = 0.f;
    const uint2* x2 = (const uint2*)xbf;
    int j = lo;
    for (; j + 4 <= hi; j += 4) {
        int s0 = srcs[j], s1 = srcs[j + 1], s2 = srcs[j + 2], s3 = srcs[j + 3];
        uint2 p0 = x2[(size_t)s0 * 32 + l];
        uint2 p1 = x2[(size_t)s1 * 32 + l];
        uint2 p2 = x2[(size_t)s2 * 32 + l];
        uint2 p3 = x2[(size_t)s3 * 32 + l];
        a0 += bf2f((unsigned short)p0.x) + bf2f((unsigned short)p1.x)
            + bf2f((unsigned short)p2.x) + bf2f((unsigned short)p3.x);
        a1 += bf2f((unsigned short)(p0.x >> 16)) + bf2f((unsigned short)(p1.x >> 16))
            + bf2f((unsigned short)(p2.x >> 16)) + bf2f((unsigned short)(p3.x >> 16));
        a2 += bf2f((unsigned short)p0.y) + bf2f((unsigned short)p1.y)
            + bf2f((unsigned short)p2.y) + bf2f((unsigned short)p3.y);
        a3 += bf2f((unsigned short)(p0.y >> 16)) + bf2f((unsigned short)(p1.y >> 16))
            + bf2f((unsigned short)(p2.y >> 16)) + bf2f((unsigned short)(p3.y >> 16));
    }
    for (; j < hi; ++j) {
        uint2 p = x2[(size_t)srcs[j] * 32 + l];
        a0 += bf2f((unsigned short)p.x); a1 += bf2f((unsigned short)(p.x >> 16));
        a2 += bf2f((unsigned short)p.y); a3 += bf2f((unsigned short)(p.y >> 16));
    }
    float iw = 1.0f / fmaxf((float)(hi - lo), 1.0f);
    uint2 o;
    o.x = ((unsigned)f2bf(a1 * iw) << 16) | (unsigned)f2bf(a0 * iw);
    o.y = ((unsigned)f2bf(a3 * iw) << 16) | (unsigned)f2bf(a2 * iw);
    ((uint2*)aggbf)[(size_t)gh * 32 + l] = o;
}

// ---------------- bf16 MFMA GEMM (GCN mixer): C = A @ BT^T + bias + res, +BN stats ----
template<bool RELU, bool HASB, bool RES, bool OUTBF, bool STATS>
__global__ __launch_bounds__(256) void k_mgemm(
    const unsigned short* __restrict__ A, const unsigned short* __restrict__ BT,
    const float* __restrict__ bias, const unsigned short* __restrict__ res,
    float* __restrict__ Cf, unsigned short* __restrict__ Cbf,
    float* __restrict__ sums, int M, int Nn, int K) {
    __shared__ short As[128 * 32];
    __shared__ short Bs[128 * 32];
    int tid = threadIdx.x;
    int lane = tid & 63;
    int wid = tid >> 6;
    int wr = wid >> 1, wc = wid & 1;
    int row0 = blockIdx.x * 128, col0 = blockIdx.y * 128;
    int lm = lane & 15, hk = lane >> 4;

    int sr = tid >> 2, ss = tid & 3;
    int wsw = sr * 32 + ((ss ^ ((sr >> 1) & 3)) << 3);
    const unsigned short* gA = A + (size_t)(row0 + sr) * K + ss * 8;
    const unsigned short* gB = BT + (size_t)(col0 + sr) * K + ss * 8;

    int oA[4], oB[4];
#pragma unroll
    for (int i = 0; i < 4; ++i) {
        int ra = wr * 64 + i * 16 + lm;
        oA[i] = ra * 32 + ((hk ^ ((ra >> 1) & 3)) << 3);
        int rb = wc * 64 + i * 16 + lm;
        oB[i] = rb * 32 + ((hk ^ ((rb >> 1) & 3)) << 3);
    }

    f32x4 acc[4][4] = {};
    for (int k0 = 0; k0 < K; k0 += 32) {
        short8 va0 = *(const short8*)(gA + k0);
        short8 va1 = *(const short8*)(gA + (size_t)64 * K + k0);
        short8 vb0 = *(const short8*)(gB + k0);
        short8 vb1 = *(const short8*)(gB + (size_t)64 * K + k0);
        __syncthreads();
        *(short8*)&As[wsw] = va0;
        *(short8*)&As[wsw + 64 * 32] = va1;
        *(short8*)&Bs[wsw] = vb0;
        *(short8*)&Bs[wsw + 64 * 32] = vb1;
        __syncthreads();
        short8 a[4], b[4];
#pragma unroll
        for (int i = 0; i < 4; ++i) a[i] = *(const short8*)&As[oA[i]];
#pragma unroll
        for (int j = 0; j < 4; ++j) b[j] = *(const short8*)&Bs[oB[j]];
#pragma unroll
        for (int i = 0; i < 4; ++i)
#pragma unroll
            for (int j = 0; j < 4; ++j)
                acc[i][j] = __builtin_amdgcn_mfma_f32_16x16x32_bf16(a[i], b[j], acc[i][j], 0, 0, 0);
    }

    float th_s[4] = {0.f, 0.f, 0.f, 0.f}, th_q[4] = {0.f, 0.f, 0.f, 0.f};
#pragma unroll
    for (int j = 0; j < 4; ++j) {
        int col = col0 + wc * 64 + j * 16 + lm;
        float bj = 0.f;
        if (HASB) bj = bias[col];
#pragma unroll
        for (int i = 0; i < 4; ++i) {
#pragma unroll
            for (int r = 0; r < 4; ++r) {
                int row = row0 + wr * 64 + i * 16 + hk * 4 + r;
                if (row < M) {
                    float v = acc[i][j][r] + bj;
                    if (RES) v += bf2f(res[(size_t)row * Nn + col]);
                    if (RELU) v = fmaxf(v, 0.f);
                    if (STATS) { th_s[j] += v; th_q[j] += v * v; }
                    if (OUTBF) Cbf[(size_t)row * Nn + col] = f2bf(v);
                    else Cf[(size_t)row * Nn + col] = v;
                }
            }
        }
    }
    if (STATS) {
#pragma unroll
        for (int j = 0; j < 4; ++j) {
            float s = th_s[j], q = th_q[j];
            s += __shfl_xor(s, 16); s += __shfl_xor(s, 32);
            q += __shfl_xor(q, 16); q += __shfl_xor(q, 32);
            if (hk == 0) {
                int col = col0 + wc * 64 + j * 16 + lm;
                atomicAdd(&sums[col], s);
                atomicAdd(&sums[128 + col], q);
            }
        }
    }
}

// ---------------- fused FF block v4: bn1 + FF1 + FF2 + res + BN2 stats ----------------
// 64 rows/block, 4 waves x 16 rows. All LDS tiles in the k_mgemm 0-conflict pattern
// ([rows][32] + XOR 16B-slot swizzle). W1/W2 chunks double-buffered, prefetched a full
// compute-phase ahead, ONE barrier per chunk. Xs fragments hoisted (loop-invariant).
#define SUBT  2064   // Xs subtile stride: 64*32 + 16
#define W1SUB 1040   // W1 subtile stride: 32*32 + 16
#define W1BUF (4 * W1SUB)
#define W2BUF 4096   // [128][32]
__global__ __launch_bounds__(256, 3) void k_ffused(
    float* __restrict__ t, const float* __restrict__ sums,
    const float* __restrict__ g, const float* __restrict__ b,
    const unsigned short* __restrict__ W1T, const float* __restrict__ b1,
    const unsigned short* __restrict__ W2T,
    float* __restrict__ sums2, int M, float invN) {
    __shared__ short Xs[4 * SUBT];      // 16.5KB bn1(t) bf16, swizzled
    __shared__ short W1s[2 * W1BUF];    // 16.6KB dbuf
    __shared__ short W2s[2 * W2BUF];    // 16.4KB dbuf
    __shared__ float sa[128], sc[128];
    __shared__ float ssum[256];

    int tid = threadIdx.x;
    int row0 = blockIdx.x * 64;

    // --- issue W chunk-0 global loads first (overlap with prologue) ---
    int row1 = tid >> 3, kb = (tid & 7) * 16;
    int row2 = tid >> 1, hb = (tid & 1) * 16;
    const unsigned short* w1g = W1T + (size_t)row1 * 128 + kb;
    const unsigned short* w2g = W2T + (size_t)row2 * 512 + hb;
    short8 pa = *(const short8*)(w1g);
    short8 pb = *(const short8*)(w1g + 8);
    short8 pcv = *(const short8*)(w2g);
    short8 pdv = *(const short8*)(w2g + 8);
    // precomputed swizzled write offsets (buf-relative)
    int w1o0, w1o1, w2o0, w2o1;
    {
        int k = kb, k0 = k >> 5, sl = (k & 31) >> 3;
        w1o0 = k0 * W1SUB + row1 * 32 + ((sl ^ ((row1 >> 1) & 3)) << 3);
        k = kb + 8; k0 = k >> 5; sl = (k & 31) >> 3;
        w1o1 = k0 * W1SUB + row1 * 32 + ((sl ^ ((row1 >> 1) & 3)) << 3);
        int sl2 = hb >> 3;
        w2o0 = row2 * 32 + ((sl2 ^ ((row2 >> 1) & 3)) << 3);
        sl2 = (hb + 8) >> 3;
        w2o1 = row2 * 32 + ((sl2 ^ ((row2 >> 1) & 3)) << 3);
    }

    if (tid < 128) {
        float m = sums[tid] * invN;
        float var = sums[128 + tid] * invN - m * m;
        float a = g[tid] * rsqrtf(var + BN_EPS);
        sa[tid] = a; sc[tid] = b[tid] - m * a;
    }
    ssum[tid] = 0.f;
    __syncthreads();

    // prologue: 64 rows of t -> bn1 -> bf16 Xs (swizzled); also write W chunk 0 -> buf0
    {
        int pc = (tid & 31) * 4;
        int pr = tid >> 5;
        int k0 = pc >> 5, cc = pc & 31;
        int slot = cc >> 3, off = cc & 7;
        float a0 = sa[pc], a1 = sa[pc + 1], a2 = sa[pc + 2], a3 = sa[pc + 3];
        float c0 = sc[pc], c1 = sc[pc + 1], c2 = sc[pc + 2], c3 = sc[pc + 3];
#pragma unroll
        for (int i = 0; i < 8; ++i) {
            int row = pr + i * 8;
            float4 v = *(const float4*)(t + (size_t)(row0 + row) * 128 + pc);
            unsigned int lo = ((unsigned)f2bf(v.y * a1 + c1) << 16) | (unsigned)f2bf(v.x * a0 + c0);
            unsigned int hi = ((unsigned)f2bf(v.w * a3 + c3) << 16) | (unsigned)f2bf(v.z * a2 + c2);
            int sw = slot ^ ((row >> 1) & 3);
            *(uint2*)&Xs[k0 * SUBT + row * 32 + sw * 8 + off] = make_uint2(lo, hi);
        }
    }
    *(short8*)&W1s[w1o0] = pa;
    *(short8*)&W1s[w1o1] = pb;
    *(short8*)&W2s[w2o0] = pcv;
    *(short8*)&W2s[w2o1] = pdv;
    __syncthreads();

    int lane = tid & 63, wv = tid >> 6;
    int lm = lane & 15, hk = lane >> 4;
    int mh = hk & 2;
    int idxA = 4 * (lm + 16 * ((2 * hk) & 3));
    int idxB = idxA + 64;
    int xrow = wv * 16 + lm;

    // hoist loop-invariant Xs fragments
    short8 xf0, xf1, xf2, xf3;
    {
        int so = ((hk ^ ((xrow >> 1) & 3)) << 3);
        xf0 = *(const short8*)&Xs[0 * SUBT + xrow * 32 + so];
        xf1 = *(const short8*)&Xs[1 * SUBT + xrow * 32 + so];
        xf2 = *(const short8*)&Xs[2 * SUBT + xrow * 32 + so];
        xf3 = *(const short8*)&Xs[3 * SUBT + xrow * 32 + so];
    }
    // fragment read offsets (buf-relative), all in the 0-conflict pattern
    int swl = ((hk ^ ((lm >> 1) & 3)) << 3);
    int o1a = lm * 32 + swl;          // W1 row = lm      (+ k0*W1SUB)
    int o1b = (16 + lm) * 32 + swl;   // W1 row = 16+lm   (same XOR: (16+lm)>>1 ≡ lm>>1 mod 4)
    int o2f[8];
#pragma unroll
    for (int nc = 0; nc < 8; ++nc) o2f[nc] = (nc * 16 + lm) * 32 + swl;

    f32x4 tacc[8] = {};
    for (int hc = 0; hc < 16; ++hc) {
        int cb = hc & 1;
        if (hc + 1 < 16) {  // prefetch next chunk into registers
            const unsigned short* g1 = w1g + (size_t)(hc + 1) * 4096;
            const unsigned short* g2 = w2g + (hc + 1) * 32;
            pa = *(const short8*)(g1);
            pb = *(const short8*)(g1 + 8);
            pcv = *(const short8*)(g2);
            pdv = *(const short8*)(g2 + 8);
        }
        // FF1 transposed: yT = W1c @ X^T (D: lm=node-row, regs=h)
        const short* W1p = &W1s[cb * W1BUF];
        f32x4 y0 = {}, y1 = {};
        y0 = __builtin_amdgcn_mfma_f32_16x16x32_bf16(*(const short8*)&W1p[o1a], xf0, y0, 0, 0, 0);
        y1 = __builtin_amdgcn_mfma_f32_16x16x32_bf16(*(const short8*)&W1p[o1b], xf0, y1, 0, 0, 0);
        y0 = __builtin_amdgcn_mfma_f32_16x16x32_bf16(*(const short8*)&W1p[W1SUB + o1a], xf1, y0, 0, 0, 0);
        y1 = __builtin_amdgcn_mfma_f32_16x16x32_bf16(*(const short8*)&W1p[W1SUB + o1b], xf1, y1, 0, 0, 0);
        y0 = __builtin_amdgcn_mfma_f32_16x16x32_bf16(*(const short8*)&W1p[2 * W1SUB + o1a], xf2, y0, 0, 0, 0);
        y1 = __builtin_amdgcn_mfma_f32_16x16x32_bf16(*(const short8*)&W1p[2 * W1SUB + o1b], xf2, y1, 0, 0, 0);
        y0 = __builtin_amdgcn_mfma_f32_16x16x32_bf16(*(const short8*)&W1p[3 * W1SUB + o1a], xf3, y0, 0, 0, 0);
        y1 = __builtin_amdgcn_mfma_f32_16x16x32_bf16(*(const short8*)&W1p[3 * W1SUB + o1b], xf3, y1, 0, 0, 0);
        // bias + relu + pack (h = hc*32 + m*16 + hk*4 + r); bias via float4 (L2)
        float4 bA = *(const float4*)(b1 + hc * 32 + hk * 4);
        float4 bB = *(const float4*)(b1 + hc * 32 + hk * 4 + 16);
        float v00 = fmaxf(y0[0] + bA.x, 0.f);
        float v01 = fmaxf(y0[1] + bA.y, 0.f);
        float v02 = fmaxf(y0[2] + bA.z, 0.f);
        float v03 = fmaxf(y0[3] + bA.w, 0.f);
        float v10 = fmaxf(y1[0] + bB.x, 0.f);
        float v11 = fmaxf(y1[1] + bB.y, 0.f);
        float v12 = fmaxf(y1[2] + bB.z, 0.f);
        float v13 = fmaxf(y1[3] + bB.w, 0.f);
        int pk00 = (int)(((unsigned)f2bf(v01) << 16) | (unsigned)f2bf(v00));
        int pk01 = (int)(((unsigned)f2bf(v03) << 16) | (unsigned)f2bf(v02));
        int pk10 = (int)(((unsigned)f2bf(v11) << 16) | (unsigned)f2bf(v10));
        int pk11 = (int)(((unsigned)f2bf(v13) << 16) | (unsigned)f2bf(v12));
        // repack: lane(lm,hk) gathers h = 8hk..8hk+7 for node-row lm
        int q0a = __builtin_amdgcn_ds_bpermute(idxA, pk00);
        int q1a = __builtin_amdgcn_ds_bpermute(idxA, pk01);
        int q2a = __builtin_amdgcn_ds_bpermute(idxA, pk10);
        int q3a = __builtin_amdgcn_ds_bpermute(idxA, pk11);
        int q0b = __builtin_amdgcn_ds_bpermute(idxB, pk00);
        int q1b = __builtin_amdgcn_ds_bpermute(idxB, pk01);
        int q2b = __builtin_amdgcn_ds_bpermute(idxB, pk10);
        int q3b = __builtin_amdgcn_ds_bpermute(idxB, pk11);
        union { int u[4]; short8 s; } yf;
        yf.u[0] = mh ? q2a : q0a;
        yf.u[1] = mh ? q3a : q1a;
        yf.u[2] = mh ? q2b : q0b;
        yf.u[3] = mh ? q3b : q1b;
        // FF2: tacc += y @ W2c (B from swizzled LDS)
        const short* W2p = &W2s[cb * W2BUF];
#pragma unroll
        for (int nc = 0; nc < 8; ++nc) {
            short8 w2f = *(const short8*)&W2p[o2f[nc]];
            tacc[nc] = __builtin_amdgcn_mfma_f32_16x16x32_bf16(yf.s, w2f, tacc[nc], 0, 0, 0);
        }
        if (hc + 1 < 16) {  // write prefetched chunk into the other buffer
            int nb = (hc + 1) & 1;
            *(short8*)&W1s[nb * W1BUF + w1o0] = pa;
            *(short8*)&W1s[nb * W1BUF + w1o1] = pb;
            *(short8*)&W2s[nb * W2BUF + w2o0] = pcv;
            *(short8*)&W2s[nb * W2BUF + w2o1] = pdv;
            __syncthreads();
        }
    }

    // epilogue: t = tacc + res(Xs), BN2 stats
#pragma unroll
    for (int nc = 0; nc < 8; ++nc) {
        int n = nc * 16 + lm;
        int k0 = n >> 5, cc = n & 31;
        int slot = cc >> 3, off = cc & 7;
        float s = 0.f, q = 0.f;
#pragma unroll
        for (int r = 0; r < 4; ++r) {
            int rloc = wv * 16 + hk * 4 + r;
            int grow = row0 + rloc;
            float res = bf2f((unsigned short)Xs[k0 * SUBT + rloc * 32 +
                                               ((slot ^ ((rloc >> 1) & 3)) << 3) + off]);
            float v = tacc[nc][r] + res;
            if (grow < M) {
                t[(size_t)grow * 128 + n] = v;
                s += v; q += v * v;
            }
        }
        s += __shfl_xor(s, 16); s += __shfl_xor(s, 32);
        q += __shfl_xor(q, 16); q += __shfl_xor(q, 32);
        if (hk == 0) {
            atomicAdd(&ssum[n], s);
            atomicAdd(&ssum[128 + n], q);
        }
    }
    __syncthreads();
    atomicAdd(&sums2[tid], ssum[tid]);
}

// ---------------- BN apply: x_bf = bf16((t - m) * a + b) ----------------
__global__ __launch_bounds__(256) void k_bnapply(
    const float* __restrict__ t, const float* __restrict__ sums,
    const float* __restrict__ g, const float* __restrict__ b,
    unsigned short* __restrict__ xbf, int N, float invN) {
    __shared__ float sa[128], sc[128];
    int tid = threadIdx.x;
    if (tid < 128) {
        float m = sums[tid] * invN;
        float var = sums[128 + tid] * invN - m * m;
        float a = g[tid] * rsqrtf(var + BN_EPS);
        sa[tid] = a; sc[tid] = b[tid] - m * a;
    }
    __syncthreads();
    int total4 = N * 32;
    for (int i = blockIdx.x * 256 + tid; i < total4; i += gridDim.x * 256) {
        int c4 = (i & 31) * 4;
        float4 v = ((const float4*)t)[i];
        float ox = v.x * sa[c4 + 0] + sc[c4 + 0];
        float oy = v.y * sa[c4 + 1] + sc[c4 + 1];
        float oz = v.z * sa[c4 + 2] + sc[c4 + 2];
        float ow = v.w * sa[c4 + 3] + sc[c4 + 3];
        uint2 pk;
        pk.x = ((unsigned)f2bf(oy) << 16) | (unsigned)f2bf(ox);
        pk.y = ((unsigned)f2bf(ow) << 16) | (unsigned)f2bf(oz);
        ((uint2*)xbf)[i] = pk;
    }
}

// ---------------- classifier: MFMA, one wave per 16-row tile ----------------
__global__ __launch_bounds__(256) void k_cls(
    const unsigned short* __restrict__ xbf, const unsigned short* __restrict__ wT,
    const float* __restrict__ bias, float* __restrict__ out, int N) {
    int wv = (blockIdx.x * 256 + threadIdx.x) >> 6;
    int lane = threadIdx.x & 63;
    int lm = lane & 15, hk = lane >> 4;
    int r0 = wv * 16;
    f32x4 acc = {};
    const unsigned short* xr = xbf + (size_t)(r0 + lm) * 128 + hk * 8;
    const unsigned short* wr = wT + lm * 128 + hk * 8;
#pragma unroll
    for (int ks = 0; ks < 4; ++ks) {
        short8 a = *(const short8*)(xr + ks * 32);
        short8 b = *(const short8*)(wr + ks * 32);
        acc = __builtin_amdgcn_mfma_f32_16x16x32_bf16(a, b, acc, 0, 0, 0);
    }
    float bv = bias[lm];
#pragma unroll
    for (int r = 0; r < 4; ++r) {
        int row = r0 + hk * 4 + r;
        if (row < N) out[(size_t)row * 16 + lm] = acc[r] + bv;
    }
}

extern "C" void kernel_launch(void* const* d_in, const int* in_sizes, int n_in,
                              void* d_out, int out_size, void* d_ws, size_t ws_size,
                              hipStream_t stream) {
    const float* nodes = (const float*)d_in[0];
    const float* W_gcn = (const float*)d_in[1];
    const float* b_gcn = (const float*)d_in[2];
    const float* bn1_g = (const float*)d_in[3];
    const float* bn1_b = (const float*)d_in[4];
    const float* bn2_g = (const float*)d_in[5];
    const float* bn2_b = (const float*)d_in[6];
    const float* ff_w1 = (const float*)d_in[7];
    const float* ff_b1 = (const float*)d_in[8];
    const float* ff_w2 = (const float*)d_in[9];
    const float* cls_w = (const float*)d_in[10];
    const float* cls_b = (const float*)d_in[11];
    const int* esrc = (const int*)d_in[12];
    const int* edst = (const int*)d_in[13];
    const int N = in_sizes[0] / 128;
    const int E = in_sizes[12];
    const int M_pad = (N + 127) & ~127;

    char* p = (char*)d_ws;
    auto alloc = [&](size_t bytes) {
        void* r = (void*)p;
        p += (bytes + 255) & ~(size_t)255;
        return r;
    };
    // zero-region: cnt | cursor | 4x sums  (one memset)
    int* cnt      = (int*)alloc((size_t)N * 4);
    int* cursor   = (int*)alloc((size_t)N * 4);
    float* sums4  = (float*)alloc(4 * 256 * 4);
    size_t zbytes = (size_t)((char*)sums4 + 4 * 256 * 4 - (char*)cnt);

    float* t    = (float*)alloc((size_t)M_pad * 128 * 4);
    int* rowptr = (int*)alloc((size_t)(N + 1) * 4);
    int* srcs   = (int*)alloc((size_t)E * 4);
    int* bsum   = (int*)alloc(SCAN_G * 4);
    int* boff   = (int*)alloc(SCAN_G * 4);
    unsigned short* nodes_bf = (unsigned short*)alloc((size_t)M_pad * 128 * 2);
    unsigned short* agg_bf   = (unsigned short*)alloc((size_t)M_pad * 128 * 2);
    unsigned short* x_bf     = (unsigned short*)alloc((size_t)M_pad * 128 * 2);
    unsigned short* WgT = (unsigned short*)alloc(2 * 128 * 128 * 2);
    unsigned short* W1T = (unsigned short*)alloc(2 * 512 * 128 * 2);
    unsigned short* W2T = (unsigned short*)alloc(2 * 128 * 512 * 2);
    unsigned short* WcT = (unsigned short*)alloc(16 * 128 * 2);

    hipMemsetAsync(cnt, 0, zbytes, stream);
    k_count<<<(E + 255) / 256, 256, 0, stream>>>(edst, cnt, E);
    k_scanA<<<SCAN_G, 256, 0, stream>>>(cnt, bsum, N);
    k_scanB<<<1, SCAN_G, 0, stream>>>(bsum, boff, rowptr, N);
    k_scanC<<<SCAN_G, 256, 0, stream>>>(cnt, boff, rowptr, N);
    k_fill<<<(E + 255) / 256, 256, 0, stream>>>(esrc, edst, rowptr, cursor, srcs, E);
    {
        int convtot = 2 * 16384 + 4 * 65536 + 2048 + N * 64;
        k_conv<<<(convtot + 255) / 256, 256, 0, stream>>>(
            W_gcn, ff_w1, ff_w2, cls_w, nodes, WgT, W1T, W2T, WcT, nodes_bf, N * 64);
    }

    const float invN = 1.0f / (float)N;
    const int MB = M_pad / 128;
    const int MB64 = M_pad / 64;
    const unsigned short* cur_bf = nodes_bf;
    for (int L = 0; L < 2; ++L) {
        k_agg<<<(N + 7) / 8, 256, 0, stream>>>(cur_bf, rowptr, srcs, agg_bf, N);
        float* s1 = sums4 + (L * 2 + 0) * 256;
        float* s2 = sums4 + (L * 2 + 1) * 256;
        // GCN: t = agg@Wg + b + res(cur_bf), f32 out, fused BN1 stats
        k_mgemm<false, true, true, false, true><<<dim3(MB, 1), 256, 0, stream>>>(
            agg_bf, WgT + (size_t)L * 16384, b_gcn + L * 128, cur_bf, t, nullptr, s1,
            N, 128, 128);
        // fused: bn1-apply + FF1 + FF2 + residual + BN2 stats
        k_ffused<<<MB64, 256, 0, stream>>>(
            t, s1, bn1_g + L * 128, bn1_b + L * 128,
            W1T + (size_t)L * 65536, ff_b1 + L * 512, W2T + (size_t)L * 65536,
            s2, N, invN);
        k_bnapply<<<1600, 256, 0, stream>>>(t, s2, bn2_g + L * 128, bn2_b + L * 128,
                                            x_bf, N, invN);
        cur_bf = x_bf;
    }
    k_cls<<<(M_pad / 16 + 3) / 4, 256, 0, stream>>>(x_bf, WcT, cls_b, (float*)d_out, N);
}

// Round 11
// 451.162 us; speedup vs baseline: 1.3457x; 1.0200x over previous
//
#include <hip/hip_runtime.h>
#include <stdint.h>

#define BN_EPS 1e-5f
#define SCAN_G 128

typedef short short8 __attribute__((ext_vector_type(8)));
typedef float f32x4 __attribute__((ext_vector_type(4)));

__device__ __forceinline__ unsigned short f2bf(float f) {
    union { float f; unsigned int u; } v; v.f = f;
    unsigned int r = v.u + 0x7FFFu + ((v.u >> 16) & 1u);
    return (unsigned short)(r >> 16);
}
__device__ __forceinline__ float bf2f(unsigned short h) {
    union { unsigned int u; float f; } v; v.u = (unsigned int)h << 16; return v.f;
}

// ---------------- CSR build ----------------
__global__ void k_count(const int* __restrict__ dst, int* __restrict__ cnt, int E) {
    int i = blockIdx.x * 256 + threadIdx.x;
    if (i < E) atomicAdd(cnt + dst[i], 1);
}

__global__ __launch_bounds__(256) void k_scanA(const int* __restrict__ cnt,
                                               int* __restrict__ bsum, int N) {
    __shared__ int red[256];
    int b = blockIdx.x, t = threadIdx.x;
    int C = (N + SCAN_G - 1) / SCAN_G;
    int c = (C + 255) >> 8;
    int lo = b * C + t * c;
    int hi = min(lo + c, min((b + 1) * C, N));
    int s = 0;
    for (int i = lo; i < hi; ++i) s += cnt[i];
    red[t] = s;
    __syncthreads();
    for (int off = 128; off > 0; off >>= 1) {
        if (t < off) red[t] += red[t + off];
        __syncthreads();
    }
    if (t == 0) bsum[b] = red[0];
}
__global__ void k_scanB(const int* __restrict__ bsum, int* __restrict__ boff,
                        int* __restrict__ rowptr, int N) {
    __shared__ int sh[SCAN_G];
    int t = threadIdx.x;
    int v = bsum[t];
    sh[t] = v;
    __syncthreads();
    for (int off = 1; off < SCAN_G; off <<= 1) {
        int add = (t >= off) ? sh[t - off] : 0;
        __syncthreads();
        sh[t] += add;
        __syncthreads();
    }
    boff[t] = sh[t] - v;
    if (t == SCAN_G - 1) rowptr[N] = sh[t];
}
__global__ __launch_bounds__(256) void k_scanC(const int* __restrict__ cnt,
                                               const int* __restrict__ boff,
                                               int* __restrict__ rowptr, int N) {
    __shared__ int sh[256];
    int b = blockIdx.x, t = threadIdx.x;
    int C = (N + SCAN_G - 1) / SCAN_G;
    int c = (C + 255) >> 8;
    int lo = b * C + t * c;
    int hi = min(lo + c, min((b + 1) * C, N));
    int s = 0;
    for (int i = lo; i < hi; ++i) s += cnt[i];
    sh[t] = s;
    __syncthreads();
    for (int off = 1; off < 256; off <<= 1) {
        int add = (t >= off) ? sh[t - off] : 0;
        __syncthreads();
        sh[t] += add;
        __syncthreads();
    }
    int run = boff[b] + sh[t] - s;
    for (int i = lo; i < hi; ++i) { rowptr[i] = run; run += cnt[i]; }
}

__global__ void k_fill(const int* __restrict__ src, const int* __restrict__ dst,
                       const int* __restrict__ rowptr, int* __restrict__ cursor,
                       int* __restrict__ srcs, int E) {
    int i = blockIdx.x * 256 + threadIdx.x;
    if (i < E) {
        int r = dst[i];
        int p = atomicAdd(cursor + r, 1);
        srcs[rowptr[r] + p] = src[i];
    }
}

// ------- combined convert: weights (transposed bf16) + cls_w + nodes bf16 -------
__global__ void k_conv(const float* __restrict__ Wg, const float* __restrict__ W1,
                       const float* __restrict__ W2, const float* __restrict__ Wc,
                       const float* __restrict__ nf,
                       unsigned short* __restrict__ WgT, unsigned short* __restrict__ W1T,
                       unsigned short* __restrict__ W2T, unsigned short* __restrict__ WcT,
                       unsigned short* __restrict__ nbf, int n2) {
    int id = blockIdx.x * 256 + threadIdx.x;
    const int A = 2 * 16384, B = A + 2 * 65536, C = B + 2 * 65536, D = C + 2048;
    if (id < A) {
        int L = id >> 14, e = id & 16383;
        int k = e >> 7, n = e & 127;
        WgT[(L << 14) + n * 128 + k] = f2bf(Wg[id]);
    } else if (id < B) {
        int t = id - A;
        int L = t >> 16, e = t & 65535;
        int k = e >> 9, n = e & 511;
        W1T[(L << 16) + n * 128 + k] = f2bf(W1[t]);
    } else if (id < C) {
        int t = id - B;
        int L = t >> 16, e = t & 65535;
        int k = e >> 7, n = e & 127;
        W2T[(L << 16) + n * 512 + k] = f2bf(W2[t]);
    } else if (id < D) {
        int t = id - C;
        int k = t >> 4, c = t & 15;
        WcT[c * 128 + k] = f2bf(Wc[t]);
    } else {
        int i = id - D;
        if (i < n2) {
            float2 v = ((const float2*)nf)[i];
            ((unsigned int*)nbf)[i] = ((unsigned int)f2bf(v.y) << 16) | (unsigned int)f2bf(v.x);
        }
    }
}

// ---------------- aggregation: one HALF-WAVE (32 lanes) per dst node ----------------
__global__ __launch_bounds__(256) void k_agg(
    const unsigned short* __restrict__ xbf, const int* __restrict__ rowptr,
    const int* __restrict__ srcs, unsigned short* __restrict__ aggbf, int N) {
    int gh = (blockIdx.x * 256 + threadIdx.x) >> 5;
    int l = threadIdx.x & 31;
    if (gh >= N) return;
    int lo = rowptr[gh], hi = rowptr[gh + 1];
    float a0 = 0.f, a1 = 0.f, a2 = 0.f, a3 = 0.f;
    const uint2* x2 = (const uint2*)xbf;
    int j = lo;
    for (; j + 4 <= hi; j += 4) {
        int s0 = srcs[j], s1 = srcs[j + 1], s2 = srcs[j + 2], s3 = srcs[j + 3];
        uint2 p0 = x2[(size_t)s0 * 32 + l];
        uint2 p1 = x2[(size_t)s1 * 32 + l];
        uint2 p2 = x2[(size_t)s2 * 32 + l];
        uint2 p3 = x2[(size_t)s3 * 32 + l];
        a0 += bf2f((unsigned short)p0.x) + bf2f((unsigned short)p1.x)
            + bf2f((unsigned short)p2.x) + bf2f((unsigned short)p3.x);
        a1 += bf2f((unsigned short)(p0.x >> 16)) + bf2f((unsigned short)(p1.x >> 16))
            + bf2f((unsigned short)(p2.x >> 16)) + bf2f((unsigned short)(p3.x >> 16));
        a2 += bf2f((unsigned short)p0.y) + bf2f((unsigned short)p1.y)
            + bf2f((unsigned short)p2.y) + bf2f((unsigned short)p3.y);
        a3 += bf2f((unsigned short)(p0.y >> 16)) + bf2f((unsigned short)(p1.y >> 16))
            + bf2f((unsigned short)(p2.y >> 16)) + bf2f((unsigned short)(p3.y >> 16));
    }
    for (; j < hi; ++j) {
        uint2 p = x2[(size_t)srcs[j] * 32 + l];
        a0 += bf2f((unsigned short)p.x); a1 += bf2f((unsigned short)(p.x >> 16));
        a2 += bf2f((unsigned short)p.y); a3 += bf2f((unsigned short)(p.y >> 16));
    }
    float iw = 1.0f / fmaxf((float)(hi - lo), 1.0f);
    uint2 o;
    o.x = ((unsigned)f2bf(a1 * iw) << 16) | (unsigned)f2bf(a0 * iw);
    o.y = ((unsigned)f2bf(a3 * iw) << 16) | (unsigned)f2bf(a2 * iw);
    ((uint2*)aggbf)[(size_t)gh * 32 + l] = o;
}

// ---------------- bf16 MFMA GEMM (GCN mixer): C = A @ BT^T + bias + res, +BN stats ----
template<bool RELU, bool HASB, bool RES, bool OUTBF, bool STATS>
__global__ __launch_bounds__(256) void k_mgemm(
    const unsigned short* __restrict__ A, const unsigned short* __restrict__ BT,
    const float* __restrict__ bias, const unsigned short* __restrict__ res,
    float* __restrict__ Cf, unsigned short* __restrict__ Cbf,
    float* __restrict__ sums, int M, int Nn, int K) {
    __shared__ short As[128 * 32];
    __shared__ short Bs[128 * 32];
    int tid = threadIdx.x;
    int lane = tid & 63;
    int wid = tid >> 6;
    int wr = wid >> 1, wc = wid & 1;
    int row0 = blockIdx.x * 128, col0 = blockIdx.y * 128;
    int lm = lane & 15, hk = lane >> 4;

    int sr = tid >> 2, ss = tid & 3;
    int wsw = sr * 32 + ((ss ^ ((sr >> 1) & 3)) << 3);
    const unsigned short* gA = A + (size_t)(row0 + sr) * K + ss * 8;
    const unsigned short* gB = BT + (size_t)(col0 + sr) * K + ss * 8;

    int oA[4], oB[4];
#pragma unroll
    for (int i = 0; i < 4; ++i) {
        int ra = wr * 64 + i * 16 + lm;
        oA[i] = ra * 32 + ((hk ^ ((ra >> 1) & 3)) << 3);
        int rb = wc * 64 + i * 16 + lm;
        oB[i] = rb * 32 + ((hk ^ ((rb >> 1) & 3)) << 3);
    }

    f32x4 acc[4][4] = {};
    for (int k0 = 0; k0 < K; k0 += 32) {
        short8 va0 = *(const short8*)(gA + k0);
        short8 va1 = *(const short8*)(gA + (size_t)64 * K + k0);
        short8 vb0 = *(const short8*)(gB + k0);
        short8 vb1 = *(const short8*)(gB + (size_t)64 * K + k0);
        __syncthreads();
        *(short8*)&As[wsw] = va0;
        *(short8*)&As[wsw + 64 * 32] = va1;
        *(short8*)&Bs[wsw] = vb0;
        *(short8*)&Bs[wsw + 64 * 32] = vb1;
        __syncthreads();
        short8 a[4], b[4];
#pragma unroll
        for (int i = 0; i < 4; ++i) a[i] = *(const short8*)&As[oA[i]];
#pragma unroll
        for (int j = 0; j < 4; ++j) b[j] = *(const short8*)&Bs[oB[j]];
#pragma unroll
        for (int i = 0; i < 4; ++i)
#pragma unroll
            for (int j = 0; j < 4; ++j)
                acc[i][j] = __builtin_amdgcn_mfma_f32_16x16x32_bf16(a[i], b[j], acc[i][j], 0, 0, 0);
    }

    float th_s[4] = {0.f, 0.f, 0.f, 0.f}, th_q[4] = {0.f, 0.f, 0.f, 0.f};
#pragma unroll
    for (int j = 0; j < 4; ++j) {
        int col = col0 + wc * 64 + j * 16 + lm;
        float bj = 0.f;
        if (HASB) bj = bias[col];
#pragma unroll
        for (int i = 0; i < 4; ++i) {
#pragma unroll
            for (int r = 0; r < 4; ++r) {
                int row = row0 + wr * 64 + i * 16 + hk * 4 + r;
                if (row < M) {
                    float v = acc[i][j][r] + bj;
                    if (RES) v += bf2f(res[(size_t)row * Nn + col]);
                    if (RELU) v = fmaxf(v, 0.f);
                    if (STATS) { th_s[j] += v; th_q[j] += v * v; }
                    if (OUTBF) Cbf[(size_t)row * Nn + col] = f2bf(v);
                    else Cf[(size_t)row * Nn + col] = v;
                }
            }
        }
    }
    if (STATS) {
#pragma unroll
        for (int j = 0; j < 4; ++j) {
            float s = th_s[j], q = th_q[j];
            s += __shfl_xor(s, 16); s += __shfl_xor(s, 32);
            q += __shfl_xor(q, 16); q += __shfl_xor(q, 32);
            if (hk == 0) {
                int col = col0 + wc * 64 + j * 16 + lm;
                atomicAdd(&sums[col], s);
                atomicAdd(&sums[128 + col], q);
            }
        }
    }
}

// ---------------- fused FF block v5: bn1 + FF1 + FF2 + res + BN2 stats ----------------
// 64 rows/block, 8 waves (512 thr) = 4 row-groups x 2 H-groups. hg0: chunks 0..7,
// hg1: chunks 8..15 (serial chain halved). Pair-buffer W staging (one buf per hg),
// register prefetch of iter i+1 overlapping compute of iter i. Final H-combine via
// LDS (reuses W region). All tiles in the 0-conflict swizzled pattern.
#define SUBT  2064   // Xs subtile stride: 64*32 + 16
#define W1SUB 1040   // W1 subtile stride: 32*32 + 16
#define W1BUF (4 * W1SUB)
#define W2BUF 4096   // [128][32]
__global__ __launch_bounds__(512, 4) void k_ffused(
    float* __restrict__ t, const float* __restrict__ sums,
    const float* __restrict__ g, const float* __restrict__ b,
    const unsigned short* __restrict__ W1T, const float* __restrict__ b1,
    const unsigned short* __restrict__ W2T,
    float* __restrict__ sums2, int M, float invN) {
    // Xs | W1 pair | W2 pair ; the W region is aliased as f32 red[] for the H-combine
    __shared__ short SM[4 * SUBT + 2 * W1BUF + 2 * W2BUF];
    short* Xs  = SM;
    short* W1s = SM + 4 * SUBT;
    short* W2s = SM + 4 * SUBT + 2 * W1BUF;
    float* red = (float*)(SM + 4 * SUBT);    // needs 4*16*128*4 = 32768B <= 33024B
    __shared__ float sa[128], sc[128];
    __shared__ float ssum[256];

    int tid = threadIdx.x;
    int row0 = blockIdx.x * 64;

    // --- staging thread mapping (chunk-independent) ---
    int rl1 = tid >> 3;              // 0..63 : W1 row across the pair
    int b1i = rl1 >> 5, rr = rl1 & 31;
    int kb  = (tid & 7) * 16;
    int row2 = tid >> 2;             // 0..127 : W2 row
    int hsel = tid & 3;
    int b2i = hsel >> 1, hb = (hsel & 1) * 16;
    const unsigned short* w1g = W1T + (size_t)(rr + b1i * 256) * 128 + kb;
    const unsigned short* w2g = W2T + (size_t)row2 * 512 + b2i * 256 + hb;
    int w1o0, w1o1, w2o0, w2o1;
    {
        int k = kb;
        w1o0 = b1i * W1BUF + (k >> 5) * W1SUB + rr * 32 + ((((k & 31) >> 3) ^ ((rr >> 1) & 3)) << 3);
        k = kb + 8;
        w1o1 = b1i * W1BUF + (k >> 5) * W1SUB + rr * 32 + ((((k & 31) >> 3) ^ ((rr >> 1) & 3)) << 3);
        w2o0 = b2i * W2BUF + row2 * 32 + (((hb >> 3) ^ ((row2 >> 1) & 3)) << 3);
        w2o1 = b2i * W2BUF + row2 * 32 + ((((hb + 8) >> 3) ^ ((row2 >> 1) & 3)) << 3);
    }

    // issue iter-0 W loads (chunks 0 and 8) to overlap the prologue
    short8 pa = *(const short8*)(w1g);
    short8 pb = *(const short8*)(w1g + 8);
    short8 pcv = *(const short8*)(w2g);
    short8 pdv = *(const short8*)(w2g + 8);

    if (tid < 128) {
        float m = sums[tid] * invN;
        float var = sums[128 + tid] * invN - m * m;
        float a = g[tid] * rsqrtf(var + BN_EPS);
        sa[tid] = a; sc[tid] = b[tid] - m * a;
    }
    if (tid < 256) ssum[tid] = 0.f;
    __syncthreads();

    // prologue: 64 rows of t -> bn1 -> bf16 Xs (swizzled); then write iter-0 W
    {
        int pc = (tid & 31) * 4;
        int pr = tid >> 5;   // 0..15
        int k0 = pc >> 5, cc = pc & 31;
        int slot = cc >> 3, off = cc & 7;
        float a0 = sa[pc], a1 = sa[pc + 1], a2 = sa[pc + 2], a3 = sa[pc + 3];
        float c0 = sc[pc], c1 = sc[pc + 1], c2 = sc[pc + 2], c3 = sc[pc + 3];
#pragma unroll
        for (int i = 0; i < 4; ++i) {
            int row = pr + i * 16;
            float4 v = *(const float4*)(t + (size_t)(row0 + row) * 128 + pc);
            unsigned int lo = ((unsigned)f2bf(v.y * a1 + c1) << 16) | (unsigned)f2bf(v.x * a0 + c0);
            unsigned int hi = ((unsigned)f2bf(v.w * a3 + c3) << 16) | (unsigned)f2bf(v.z * a2 + c2);
            int sw = slot ^ ((row >> 1) & 3);
            *(uint2*)&Xs[k0 * SUBT + row * 32 + sw * 8 + off] = make_uint2(lo, hi);
        }
    }
    *(short8*)&W1s[w1o0] = pa;
    *(short8*)&W1s[w1o1] = pb;
    *(short8*)&W2s[w2o0] = pcv;
    *(short8*)&W2s[w2o1] = pdv;
    __syncthreads();

    int lane = tid & 63, wv = tid >> 6;
    int rg = wv & 3, hg = wv >> 2;        // row-group 0..3, H-group 0..1
    int lm = lane & 15, hk = lane >> 4;
    int mh = hk & 2;
    int idxA = 4 * (lm + 16 * ((2 * hk) & 3));
    int idxB = idxA + 64;
    int xrow = rg * 16 + lm;

    // hoist loop-invariant Xs fragments
    short8 xf0, xf1, xf2, xf3;
    {
        int so = ((hk ^ ((xrow >> 1) & 3)) << 3);
        xf0 = *(const short8*)&Xs[0 * SUBT + xrow * 32 + so];
        xf1 = *(const short8*)&Xs[1 * SUBT + xrow * 32 + so];
        xf2 = *(const short8*)&Xs[2 * SUBT + xrow * 32 + so];
        xf3 = *(const short8*)&Xs[3 * SUBT + xrow * 32 + so];
    }
    int swl = ((hk ^ ((lm >> 1) & 3)) << 3);
    int o1a = lm * 32 + swl;
    int o1b = (16 + lm) * 32 + swl;
    int o2f[8];
#pragma unroll
    for (int nc = 0; nc < 8; ++nc) o2f[nc] = (nc * 16 + lm) * 32 + swl;

    const short* W1p = &W1s[hg * W1BUF];
    const short* W2p = &W2s[hg * W2BUF];
    const float* b1g = b1 + hg * 256;

    f32x4 tacc[8] = {};
    for (int i = 0; i < 8; ++i) {
        if (i + 1 < 8) {   // prefetch iter i+1 (chunks i+1 and 8+i+1) into regs
            const unsigned short* g1 = w1g + (size_t)(i + 1) * 4096;
            const unsigned short* g2 = w2g + (i + 1) * 32;
            pa = *(const short8*)(g1);
            pb = *(const short8*)(g1 + 8);
            pcv = *(const short8*)(g2);
            pdv = *(const short8*)(g2 + 8);
        }
        // FF1 transposed: yT = W1c @ X^T (D: lm=node-row, regs=h)
        f32x4 y0 = {}, y1 = {};
        y0 = __builtin_amdgcn_mfma_f32_16x16x32_bf16(*(const short8*)&W1p[o1a], xf0, y0, 0, 0, 0);
        y1 = __builtin_amdgcn_mfma_f32_16x16x32_bf16(*(const short8*)&W1p[o1b], xf0, y1, 0, 0, 0);
        y0 = __builtin_amdgcn_mfma_f32_16x16x32_bf16(*(const short8*)&W1p[W1SUB + o1a], xf1, y0, 0, 0, 0);
        y1 = __builtin_amdgcn_mfma_f32_16x16x32_bf16(*(const short8*)&W1p[W1SUB + o1b], xf1, y1, 0, 0, 0);
        y0 = __builtin_amdgcn_mfma_f32_16x16x32_bf16(*(const short8*)&W1p[2 * W1SUB + o1a], xf2, y0, 0, 0, 0);
        y1 = __builtin_amdgcn_mfma_f32_16x16x32_bf16(*(const short8*)&W1p[2 * W1SUB + o1b], xf2, y1, 0, 0, 0);
        y0 = __builtin_amdgcn_mfma_f32_16x16x32_bf16(*(const short8*)&W1p[3 * W1SUB + o1a], xf3, y0, 0, 0, 0);
        y1 = __builtin_amdgcn_mfma_f32_16x16x32_bf16(*(const short8*)&W1p[3 * W1SUB + o1b], xf3, y1, 0, 0, 0);
        // bias + relu + pack (h = (hg*8+i)*32 + m*16 + hk*4 + r)
        float4 bA = *(const float4*)(b1g + i * 32 + hk * 4);
        float4 bB = *(const float4*)(b1g + i * 32 + hk * 4 + 16);
        float v00 = fmaxf(y0[0] + bA.x, 0.f);
        float v01 = fmaxf(y0[1] + bA.y, 0.f);
        float v02 = fmaxf(y0[2] + bA.z, 0.f);
        float v03 = fmaxf(y0[3] + bA.w, 0.f);
        float v10 = fmaxf(y1[0] + bB.x, 0.f);
        float v11 = fmaxf(y1[1] + bB.y, 0.f);
        float v12 = fmaxf(y1[2] + bB.z, 0.f);
        float v13 = fmaxf(y1[3] + bB.w, 0.f);
        int pk00 = (int)(((unsigned)f2bf(v01) << 16) | (unsigned)f2bf(v00));
        int pk01 = (int)(((unsigned)f2bf(v03) << 16) | (unsigned)f2bf(v02));
        int pk10 = (int)(((unsigned)f2bf(v11) << 16) | (unsigned)f2bf(v10));
        int pk11 = (int)(((unsigned)f2bf(v13) << 16) | (unsigned)f2bf(v12));
        // repack: lane(lm,hk) gathers h = 8hk..8hk+7 for node-row lm
        int q0a = __builtin_amdgcn_ds_bpermute(idxA, pk00);
        int q1a = __builtin_amdgcn_ds_bpermute(idxA, pk01);
        int q2a = __builtin_amdgcn_ds_bpermute(idxA, pk10);
        int q3a = __builtin_amdgcn_ds_bpermute(idxA, pk11);
        int q0b = __builtin_amdgcn_ds_bpermute(idxB, pk00);
        int q1b = __builtin_amdgcn_ds_bpermute(idxB, pk01);
        int q2b = __builtin_amdgcn_ds_bpermute(idxB, pk10);
        int q3b = __builtin_amdgcn_ds_bpermute(idxB, pk11);
        union { int u[4]; short8 s; } yf;
        yf.u[0] = mh ? q2a : q0a;
        yf.u[1] = mh ? q3a : q1a;
        yf.u[2] = mh ? q2b : q0b;
        yf.u[3] = mh ? q3b : q1b;
        // FF2: tacc += y @ W2c
#pragma unroll
        for (int nc = 0; nc < 8; ++nc) {
            short8 w2f = *(const short8*)&W2p[o2f[nc]];
            tacc[nc] = __builtin_amdgcn_mfma_f32_16x16x32_bf16(yf.s, w2f, tacc[nc], 0, 0, 0);
        }
        if (i + 1 < 8) {
            __syncthreads();   // everyone done reading W bufs for iter i
            *(short8*)&W1s[w1o0] = pa;
            *(short8*)&W1s[w1o1] = pb;
            *(short8*)&W2s[w2o0] = pcv;
            *(short8*)&W2s[w2o1] = pdv;
            __syncthreads();   // iter i+1 W ready
        }
    }

    // ---- H-combine: hg1 parks tacc in LDS (reusing W region), hg0 adds ----
    __syncthreads();
    if (hg == 1) {
#pragma unroll
        for (int nc = 0; nc < 8; ++nc)
#pragma unroll
            for (int r = 0; r < 4; ++r)
                red[rg * 2048 + (hk * 4 + r) * 128 + nc * 16 + lm] = tacc[nc][r];
    }
    __syncthreads();
    if (hg == 0) {
#pragma unroll
        for (int nc = 0; nc < 8; ++nc) {
            int n = nc * 16 + lm;
            int k0 = n >> 5, cc = n & 31;
            int slot = cc >> 3, off = cc & 7;
            float s = 0.f, q = 0.f;
#pragma unroll
            for (int r = 0; r < 4; ++r) {
                int rloc = rg * 16 + hk * 4 + r;
                int grow = row0 + rloc;
                float other = red[rg * 2048 + (hk * 4 + r) * 128 + n];
                float res = bf2f((unsigned short)Xs[k0 * SUBT + rloc * 32 +
                                                   ((slot ^ ((rloc >> 1) & 3)) << 3) + off]);
                float v = tacc[nc][r] + other + res;
                if (grow < M) {
                    t[(size_t)grow * 128 + n] = v;
                    s += v; q += v * v;
                }
            }
            s += __shfl_xor(s, 16); s += __shfl_xor(s, 32);
            q += __shfl_xor(q, 16); q += __shfl_xor(q, 32);
            if (hk == 0) {
                atomicAdd(&ssum[n], s);
                atomicAdd(&ssum[128 + n], q);
            }
        }
    }
    __syncthreads();
    if (tid < 256) atomicAdd(&sums2[tid], ssum[tid]);
}

// ---------------- BN apply: x_bf = bf16((t - m) * a + b) ----------------
__global__ __launch_bounds__(256) void k_bnapply(
    const float* __restrict__ t, const float* __restrict__ sums,
    const float* __restrict__ g, const float* __restrict__ b,
    unsigned short* __restrict__ xbf, int N, float invN) {
    __shared__ float sa[128], sc[128];
    int tid = threadIdx.x;
    if (tid < 128) {
        float m = sums[tid] * invN;
        float var = sums[128 + tid] * invN - m * m;
        float a = g[tid] * rsqrtf(var + BN_EPS);
        sa[tid] = a; sc[tid] = b[tid] - m * a;
    }
    __syncthreads();
    int total4 = N * 32;
    for (int i = blockIdx.x * 256 + tid; i < total4; i += gridDim.x * 256) {
        int c4 = (i & 31) * 4;
        float4 v = ((const float4*)t)[i];
        float ox = v.x * sa[c4 + 0] + sc[c4 + 0];
        float oy = v.y * sa[c4 + 1] + sc[c4 + 1];
        float oz = v.z * sa[c4 + 2] + sc[c4 + 2];
        float ow = v.w * sa[c4 + 3] + sc[c4 + 3];
        uint2 pk;
        pk.x = ((unsigned)f2bf(oy) << 16) | (unsigned)f2bf(ox);
        pk.y = ((unsigned)f2bf(ow) << 16) | (unsigned)f2bf(oz);
        ((uint2*)xbf)[i] = pk;
    }
}

// ---------------- classifier: MFMA, one wave per 16-row tile ----------------
__global__ __launch_bounds__(256) void k_cls(
    const unsigned short* __restrict__ xbf, const unsigned short* __restrict__ wT,
    const float* __restrict__ bias, float* __restrict__ out, int N) {
    int wv = (blockIdx.x * 256 + threadIdx.x) >> 6;
    int lane = threadIdx.x & 63;
    int lm = lane & 15, hk = lane >> 4;
    int r0 = wv * 16;
    f32x4 acc = {};
    const unsigned short* xr = xbf + (size_t)(r0 + lm) * 128 + hk * 8;
    const unsigned short* wr = wT + lm * 128 + hk * 8;
#pragma unroll
    for (int ks = 0; ks < 4; ++ks) {
        short8 a = *(const short8*)(xr + ks * 32);
        short8 b = *(const short8*)(wr + ks * 32);
        acc = __builtin_amdgcn_mfma_f32_16x16x32_bf16(a, b, acc, 0, 0, 0);
    }
    float bv = bias[lm];
#pragma unroll
    for (int r = 0; r < 4; ++r) {
        int row = r0 + hk * 4 + r;
        if (row < N) out[(size_t)row * 16 + lm] = acc[r] + bv;
    }
}

extern "C" void kernel_launch(void* const* d_in, const int* in_sizes, int n_in,
                              void* d_out, int out_size, void* d_ws, size_t ws_size,
                              hipStream_t stream) {
    const float* nodes = (const float*)d_in[0];
    const float* W_gcn = (const float*)d_in[1];
    const float* b_gcn = (const float*)d_in[2];
    const float* bn1_g = (const float*)d_in[3];
    const float* bn1_b = (const float*)d_in[4];
    const float* bn2_g = (const float*)d_in[5];
    const float* bn2_b = (const float*)d_in[6];
    const float* ff_w1 = (const float*)d_in[7];
    const float* ff_b1 = (const float*)d_in[8];
    const float* ff_w2 = (const float*)d_in[9];
    const float* cls_w = (const float*)d_in[10];
    const float* cls_b = (const float*)d_in[11];
    const int* esrc = (const int*)d_in[12];
    const int* edst = (const int*)d_in[13];
    const int N = in_sizes[0] / 128;
    const int E = in_sizes[12];
    const int M_pad = (N + 127) & ~127;

    char* p = (char*)d_ws;
    auto alloc = [&](size_t bytes) {
        void* r = (void*)p;
        p += (bytes + 255) & ~(size_t)255;
        return r;
    };
    // zero-region: cnt | cursor | 4x sums  (one memset)
    int* cnt      = (int*)alloc((size_t)N * 4);
    int* cursor   = (int*)alloc((size_t)N * 4);
    float* sums4  = (float*)alloc(4 * 256 * 4);
    size_t zbytes = (size_t)((char*)sums4 + 4 * 256 * 4 - (char*)cnt);

    float* t    = (float*)alloc((size_t)M_pad * 128 * 4);
    int* rowptr = (int*)alloc((size_t)(N + 1) * 4);
    int* srcs   = (int*)alloc((size_t)E * 4);
    int* bsum   = (int*)alloc(SCAN_G * 4);
    int* boff   = (int*)alloc(SCAN_G * 4);
    unsigned short* nodes_bf = (unsigned short*)alloc((size_t)M_pad * 128 * 2);
    unsigned short* agg_bf   = (unsigned short*)alloc((size_t)M_pad * 128 * 2);
    unsigned short* x_bf     = (unsigned short*)alloc((size_t)M_pad * 128 * 2);
    unsigned short* WgT = (unsigned short*)alloc(2 * 128 * 128 * 2);
    unsigned short* W1T = (unsigned short*)alloc(2 * 512 * 128 * 2);
    unsigned short* W2T = (unsigned short*)alloc(2 * 128 * 512 * 2);
    unsigned short* WcT = (unsigned short*)alloc(16 * 128 * 2);

    hipMemsetAsync(cnt, 0, zbytes, stream);
    k_count<<<(E + 255) / 256, 256, 0, stream>>>(edst, cnt, E);
    k_scanA<<<SCAN_G, 256, 0, stream>>>(cnt, bsum, N);
    k_scanB<<<1, SCAN_G, 0, stream>>>(bsum, boff, rowptr, N);
    k_scanC<<<SCAN_G, 256, 0, stream>>>(cnt, boff, rowptr, N);
    k_fill<<<(E + 255) / 256, 256, 0, stream>>>(esrc, edst, rowptr, cursor, srcs, E);
    {
        int convtot = 2 * 16384 + 4 * 65536 + 2048 + N * 64;
        k_conv<<<(convtot + 255) / 256, 256, 0, stream>>>(
            W_gcn, ff_w1, ff_w2, cls_w, nodes, WgT, W1T, W2T, WcT, nodes_bf, N * 64);
    }

    const float invN = 1.0f / (float)N;
    const int MB = M_pad / 128;
    const int MB64 = M_pad / 64;
    const unsigned short* cur_bf = nodes_bf;
    for (int L = 0; L < 2; ++L) {
        k_agg<<<(N + 7) / 8, 256, 0, stream>>>(cur_bf, rowptr, srcs, agg_bf, N);
        float* s1 = sums4 + (L * 2 + 0) * 256;
        float* s2 = sums4 + (L * 2 + 1) * 256;
        // GCN: t = agg@Wg + b + res(cur_bf), f32 out, fused BN1 stats
        k_mgemm<false, true, true, false, true><<<dim3(MB, 1), 256, 0, stream>>>(
            agg_bf, WgT + (size_t)L * 16384, b_gcn + L * 128, cur_bf, t, nullptr, s1,
            N, 128, 128);
        // fused: bn1-apply + FF1 + FF2 + residual + BN2 stats (H split across waves)
        k_ffused<<<MB64, 512, 0, stream>>>(
            t, s1, bn1_g + L * 128, bn1_b + L * 128,
            W1T + (size_t)L * 65536, ff_b1 + L * 512, W2T + (size_t)L * 65536,
            s2, N, invN);
        k_bnapply<<<1600, 256, 0, stream>>>(t, s2, bn2_g + L * 128, bn2_b + L * 128,
                                            x_bf, N, invN);
        cur_bf = x_bf;
    }
    k_cls<<<(M_pad / 16 + 3) / 4, 256, 0, stream>>>(x_bf, WcT, cls_b, (float*)d_out, N);
}